// Round 14
// baseline (21012.892 us; speedup 1.0000x reference)
//
#include <hip/hip_runtime.h>
#include <hip/hip_fp16.h>
#include <math.h>

#define T_SEQ  512
#define BATCH  128
#define HID    256
#define NCLS   20
#define G4     1024   // 4*HID

typedef _Float16 v2h __attribute__((ext_vector_type(2)));

// ---------------------------------------------------------------------------
// Kernel A: batched input projection (unchanged from v13, proven).
// xw[dir][s][b][col] = emb[token]@W + bias
// ---------------------------------------------------------------------------
__global__ __launch_bounds__(256) void xw_gemm_v14(
    const int*   __restrict__ tokens,
    const float* __restrict__ emb_table,
    const float* __restrict__ W_f, const float* __restrict__ b_f,
    const float* __restrict__ W_b, const float* __restrict__ b_b,
    float* __restrict__ xw, int chunk0, int chunk_len)
{
    const int dir = blockIdx.z;
    const float* __restrict__ W    = dir ? W_b : W_f;
    const float* __restrict__ bias = dir ? b_b : b_f;
    const int mtile = blockIdx.x;
    const int ntile = blockIdx.y;
    const int tid = threadIdx.x;

    __shared__ float At[256][32];
    __shared__ float Bs[32][128];
    __shared__ int   tok[32];

    if (tid < 32) {
        int m = mtile * 32 + tid;
        int s_local = m >> 7;
        int b = m & 127;
        int tt = chunk0 + s_local;
        if (dir) tt = T_SEQ - 1 - tt;
        int token = tokens[b * T_SEQ + tt];
        tok[tid] = token < 0 ? 0 : (token > 49999 ? 49999 : token);
    }
    __syncthreads();

    {
        int r = tid >> 3, c8 = tid & 7;
        const float4* src = (const float4*)(emb_table + (size_t)tok[r] * 256);
        #pragma unroll
        for (int i = 0; i < 8; ++i) {
            int c4 = c8 + i * 8;
            float4 v = src[c4];
            int k0 = c4 * 4;
            At[k0 + 0][r] = v.x; At[k0 + 1][r] = v.y;
            At[k0 + 2][r] = v.z; At[k0 + 3][r] = v.w;
        }
    }

    const int r0 = (tid >> 6) * 8;
    const int col0 = tid & 63;
    float acc0[8], acc1[8];
    {
        float bv0 = bias[ntile * 128 + col0];
        float bv1 = bias[ntile * 128 + col0 + 64];
        #pragma unroll
        for (int i = 0; i < 8; ++i) { acc0[i] = bv0; acc1[i] = bv1; }
    }

    for (int kc = 0; kc < 8; ++kc) {
        __syncthreads();
        #pragma unroll
        for (int i = 0; i < 4; ++i) {
            int idx = tid + i * 256;
            int row = idx >> 5, c4 = idx & 31;
            *(float4*)&Bs[row][c4 * 4] =
                *(const float4*)&W[(size_t)(kc * 32 + row) * G4 + ntile * 128 + c4 * 4];
        }
        __syncthreads();
        #pragma unroll 8
        for (int k = 0; k < 32; ++k) {
            float4 a0 = *(const float4*)&At[kc * 32 + k][r0];
            float4 a1 = *(const float4*)&At[kc * 32 + k][r0 + 4];
            float bb0 = Bs[k][col0];
            float bb1 = Bs[k][col0 + 64];
            acc0[0] = fmaf(a0.x, bb0, acc0[0]); acc1[0] = fmaf(a0.x, bb1, acc1[0]);
            acc0[1] = fmaf(a0.y, bb0, acc0[1]); acc1[1] = fmaf(a0.y, bb1, acc1[1]);
            acc0[2] = fmaf(a0.z, bb0, acc0[2]); acc1[2] = fmaf(a0.z, bb1, acc1[2]);
            acc0[3] = fmaf(a0.w, bb0, acc0[3]); acc1[3] = fmaf(a0.w, bb1, acc1[3]);
            acc0[4] = fmaf(a1.x, bb0, acc0[4]); acc1[4] = fmaf(a1.x, bb1, acc1[4]);
            acc0[5] = fmaf(a1.y, bb0, acc0[5]); acc1[5] = fmaf(a1.y, bb1, acc1[5]);
            acc0[6] = fmaf(a1.z, bb0, acc0[6]); acc1[6] = fmaf(a1.z, bb1, acc1[6]);
            acc0[7] = fmaf(a1.w, bb0, acc0[7]); acc1[7] = fmaf(a1.w, bb1, acc1[7]);
        }
    }

    #pragma unroll
    for (int i = 0; i < 8; ++i) {
        int m = mtile * 32 + r0 + i;
        int s_local = m >> 7, b = m & 127;
        size_t base = (((size_t)dir * chunk_len + s_local) * BATCH + b) * G4 + ntile * 128;
        xw[base + col0] = acc0[i];
        xw[base + col0 + 64] = acc1[i];
    }
}

// ---------------------------------------------------------------------------
// Persistent scan kernel. Grid (rt=16, ut=16, dir=2) = 512 blocks x 256 thr,
// 2 blocks/CU guaranteed resident (38 KB LDS, <=2 waves/SIMD).
// Block owns: 8 batch rows x 16 hidden units (64 gate-cols), one direction.
// U slice cached in LDS ONCE as f16 pairs over k; h exchanged through global
// with a 16-block group barrier per step (groups = (rt,dir), independent).
// c lives in registers for the whole chunk.
// ---------------------------------------------------------------------------
__global__ __launch_bounds__(256) void lstm_scan_v14(
    const float* __restrict__ xw,        // [2][chunk][128][1024]
    const float* __restrict__ U_f, const float* __restrict__ U_b,
    float* __restrict__ hA, float* __restrict__ hB,   // [2][128][256] each
    float* __restrict__ c_state,                       // [2][128][256]
    unsigned* __restrict__ bar,                        // 32 groups x 32 dwords
    int chunk_len)
{
    const int rt  = blockIdx.x;       // 0..15 : rows rt*8..rt*8+7
    const int ut  = blockIdx.y;       // 0..15 : units ut*16..ut*16+15
    const int dir = blockIdx.z;
    const int tid = threadIdx.x;
    const float* __restrict__ U = dir ? U_b : U_f;

    __shared__ unsigned u16[128][64];     // (U[2kp][gc],U[2kp+1][gc]) f16x2, 32 KB
    __shared__ unsigned hs16[8][132];     // h as f16x2 pairs over k, padded
    __shared__ float    zs[4][8][16];     // z tile

    // ---- stage U slice -> LDS f16 pairs (once) ----
    for (int idx = tid; idx < 128 * 64; idx += 256) {
        int kp = idx >> 6;
        int c  = idx & 63;                       // g*16 + u
        int gc = (c >> 4) * 256 + ut * 16 + (c & 15);
        float a = U[(size_t)(2 * kp)     * G4 + gc];
        float b = U[(size_t)(2 * kp + 1) * G4 + gc];
        __half2 hh = __floats2half2_rn(a, b);
        u16[kp][c] = *(unsigned*)&hh;
    }

    // ---- per-thread roles ----
    const int g  = tid >> 6;          // gate (wave-uniform)
    const int r  = (tid >> 3) & 7;    // row in tile
    const int u2 = tid & 7;           // unit-pair -> local cols u2*2, u2*2+1
    const int cA = g * 16 + u2 * 2;

    // phase-2 role (threads 0..127): (r2, uu)
    const int r2 = tid >> 4;
    const int uu = tid & 15;
    float creg = 0.0f;
    if (tid < 128)
        creg = c_state[((size_t)dir * BATCH + rt * 8 + r2) * HID + ut * 16 + uu];

    // group barrier pointers: group = dir*16 + rt, 16 participants
    unsigned* cnt = bar + (dir * 16 + rt) * 32;
    unsigned* gen = cnt + 16;

    const float* hbufs[2] = {hA, hB};
    float*       hbufsw[2] = {hA, hB};

    __syncthreads();   // U staged

    int p = 0;   // read parity
    for (int s = 0; s < chunk_len; ++s) {
        // ---- stage h (f32 global -> f16x2 LDS) ----
        const float* hin = hbufs[p];
        for (int idx = tid; idx < 8 * 128; idx += 256) {
            int rr = idx >> 7, kp = idx & 127;
            float2 hv = *(const float2*)&hin[((size_t)dir * BATCH + rt * 8 + rr) * HID + 2 * kp];
            __half2 hh = __floats2half2_rn(hv.x, hv.y);
            hs16[rr][kp] = *(unsigned*)&hh;
        }
        __syncthreads();

        // ---- phase 1: z = xw + h@U for 2 cols ----
        float2 xv = *(const float2*)&xw[(((size_t)dir * chunk_len + s) * BATCH + rt * 8 + r) * G4
                                        + g * 256 + ut * 16 + u2 * 2];
        float acc0 = xv.x, acc1 = xv.y;
        #pragma unroll 16
        for (int kp = 0; kp < 128; ++kp) {
            unsigned hp = hs16[r][kp];
            unsigned ua = u16[kp][cA];
            unsigned ub = u16[kp][cA + 1];
#if __has_builtin(__builtin_amdgcn_fdot2)
            v2h hv = __builtin_bit_cast(v2h, hp);
            acc0 = __builtin_amdgcn_fdot2(hv, __builtin_bit_cast(v2h, ua), acc0, false);
            acc1 = __builtin_amdgcn_fdot2(hv, __builtin_bit_cast(v2h, ub), acc1, false);
#else
            __half2 h2 = __builtin_bit_cast(__half2, hp);
            __half2 a2 = __builtin_bit_cast(__half2, ua);
            __half2 b2 = __builtin_bit_cast(__half2, ub);
            float h0 = __low2float(h2), h1 = __high2float(h2);
            acc0 = fmaf(h0, __low2float(a2), acc0);
            acc0 = fmaf(h1, __high2float(a2), acc0);
            acc1 = fmaf(h0, __low2float(b2), acc1);
            acc1 = fmaf(h1, __high2float(b2), acc1);
#endif
        }
        zs[g][r][u2 * 2]     = acc0;
        zs[g][r][u2 * 2 + 1] = acc1;
        __syncthreads();

        // ---- phase 2: gates -> c,h (threads 0..127 own (r2,uu)) ----
        if (tid < 128) {
            float zi = zs[0][r2][uu];
            float zf = zs[1][r2][uu];
            float zg = zs[2][r2][uu];
            float zo = zs[3][r2][uu];
            float si = 1.0f / (1.0f + expf(-zi));
            float sf = 1.0f / (1.0f + expf(-zf));
            float tg = tanhf(zg);
            float so = 1.0f / (1.0f + expf(-zo));
            creg = fmaf(sf, creg, si * tg);
            float hv = so * tanhf(creg);
            hbufsw[p ^ 1][((size_t)dir * BATCH + rt * 8 + r2) * HID + ut * 16 + uu] = hv;
        }

        // ---- group barrier (16 blocks of (rt,dir)) ----
        __syncthreads();
        if (tid == 0) {
            __threadfence();
            unsigned gg  = __hip_atomic_load(gen, __ATOMIC_RELAXED, __HIP_MEMORY_SCOPE_AGENT);
            unsigned old = __hip_atomic_fetch_add(cnt, 1u, __ATOMIC_ACQ_REL, __HIP_MEMORY_SCOPE_AGENT);
            if (old == 15u) {
                __hip_atomic_store(cnt, 0u, __ATOMIC_RELAXED, __HIP_MEMORY_SCOPE_AGENT);
                __hip_atomic_fetch_add(gen, 1u, __ATOMIC_RELEASE, __HIP_MEMORY_SCOPE_AGENT);
            } else {
                while (__hip_atomic_load(gen, __ATOMIC_ACQUIRE, __HIP_MEMORY_SCOPE_AGENT) == gg) {}
            }
            __threadfence();
        }
        __syncthreads();
        p ^= 1;
    }

    if (tid < 128)
        c_state[((size_t)dir * BATCH + rt * 8 + r2) * HID + ut * 16 + uu] = creg;
}

// ---------------------------------------------------------------------------
// Fallback per-step kernel (v12 path) for tiny workspace.
// ---------------------------------------------------------------------------
__global__ __launch_bounds__(256) void lstm_step_fb(
    const int*   __restrict__ tokens,
    const float* __restrict__ emb_table,
    const float* __restrict__ W_f, const float* __restrict__ U_f, const float* __restrict__ b_f,
    const float* __restrict__ W_b, const float* __restrict__ U_b, const float* __restrict__ b_b,
    const float* __restrict__ h_in, float* __restrict__ h_out,
    float* __restrict__ c_state, int step)
{
    const int rt  = blockIdx.x;
    const int ut  = blockIdx.y;
    const int dir = blockIdx.z;
    const int tid = threadIdx.x;
    const float* __restrict__ W  = dir ? W_b : W_f;
    const float* __restrict__ U  = dir ? U_b : U_f;
    const float* __restrict__ bs = dir ? b_b : b_f;

    __shared__ int   tok[8];
    __shared__ float xs[8][260];
    __shared__ float hs[8][260];
    __shared__ float zsf[4][8][32];

    const int tt = dir ? (T_SEQ - 1 - step) : step;
    if (tid < 8) {
        int token = tokens[(rt * 8 + tid) * T_SEQ + tt];
        tok[tid] = (token < 0) ? 0 : (token > 49999 ? 49999 : token);
    }
    __syncthreads();
    for (int i = tid; i < 2048; i += 256) {
        int r = i >> 8, k = i & 255;
        xs[r][k] = emb_table[(size_t)tok[r] * 256 + k];
        hs[r][k] = h_in[((size_t)dir * BATCH + rt * 8 + r) * HID + k];
    }
    __syncthreads();

    const int g = tid >> 6, r = (tid >> 3) & 7, q = tid & 7;
    const int col = g * 256 + ut * 32 + q * 4;
    const float4* __restrict__ W4 = (const float4*)(W + col);
    const float4* __restrict__ U4 = (const float4*)(U + col);
    float4 acc = *(const float4*)(bs + col);
    #pragma unroll 4
    for (int k = 0; k < 256; ++k) {
        float xv = xs[r][k], hv = hs[r][k];
        float4 w = W4[(size_t)k * 256];
        float4 u = U4[(size_t)k * 256];
        acc.x = fmaf(xv, w.x, acc.x); acc.y = fmaf(xv, w.y, acc.y);
        acc.z = fmaf(xv, w.z, acc.z); acc.w = fmaf(xv, w.w, acc.w);
        acc.x = fmaf(hv, u.x, acc.x); acc.y = fmaf(hv, u.y, acc.y);
        acc.z = fmaf(hv, u.z, acc.z); acc.w = fmaf(hv, u.w, acc.w);
    }
    *(float4*)&zsf[g][r][q * 4] = acc;
    __syncthreads();
    {
        const int r2 = tid >> 5, j2 = tid & 31;
        float si = 1.0f / (1.0f + expf(-zsf[0][r2][j2]));
        float sf = 1.0f / (1.0f + expf(-zsf[1][r2][j2]));
        float tg = tanhf(zsf[2][r2][j2]);
        float so = 1.0f / (1.0f + expf(-zsf[3][r2][j2]));
        size_t idx = ((size_t)dir * BATCH + rt * 8 + r2) * HID + ut * 32 + j2;
        float cv = fmaf(sf, c_state[idx], si * tg);
        c_state[idx] = cv;
        h_out[idx] = so * tanhf(cv);
    }
}

// ---------------------------------------------------------------------------
// Dense + softmax (f32): one block per batch row.
// ---------------------------------------------------------------------------
__global__ __launch_bounds__(64) void dense_softmax_v14(
    const float* __restrict__ h_final,
    const float* __restrict__ W_d, const float* __restrict__ b_d,
    float* __restrict__ out)
{
    const int rrow = blockIdx.x;
    const int cth  = threadIdx.x;
    __shared__ float lg[NCLS];
    if (cth < NCLS) {
        const float* hf = h_final + (size_t)rrow * HID;
        const float* hb = h_final + ((size_t)BATCH + rrow) * HID;
        float s = b_d[cth];
        for (int k = 0; k < HID; ++k) s = fmaf(hf[k], W_d[k * NCLS + cth], s);
        for (int k = 0; k < HID; ++k) s = fmaf(hb[k], W_d[(HID + k) * NCLS + cth], s);
        lg[cth] = s;
    }
    __syncthreads();
    if (cth == 0) {
        float m = lg[0];
        for (int c = 1; c < NCLS; ++c) m = fmaxf(m, lg[c]);
        float e[NCLS]; float ssum = 0.0f;
        for (int c = 0; c < NCLS; ++c) { e[c] = expf(lg[c] - m); ssum += e[c]; }
        float inv = 1.0f / ssum;
        for (int c = 0; c < NCLS; ++c) out[rrow * NCLS + c] = e[c] * inv;
    }
}

extern "C" void kernel_launch(void* const* d_in, const int* in_sizes, int n_in,
                              void* d_out, int out_size, void* d_ws, size_t ws_size,
                              hipStream_t stream)
{
    const int*   tokens = (const int*)d_in[0];
    const float* emb    = (const float*)d_in[1];
    const float* W_f    = (const float*)d_in[2];
    const float* U_f    = (const float*)d_in[3];
    const float* b_f    = (const float*)d_in[4];
    const float* W_b    = (const float*)d_in[5];
    const float* U_b    = (const float*)d_in[6];
    const float* b_b    = (const float*)d_in[7];
    const float* W_d    = (const float*)d_in[8];
    const float* b_d    = (const float*)d_in[9];
    float* out = (float*)d_out;
    float* ws  = (float*)d_ws;

    const size_t HSLOT = (size_t)2 * BATCH * HID;        // 65536 floats
    const size_t BARSZ = 32 * 32;                        // dwords
    int chunk = 0;
    const int cand[3] = {512, 64, 16};
    for (int i = 0; i < 3; ++i) {
        size_t need = ((size_t)2 * cand[i] * BATCH * G4 + 3 * HSLOT + BARSZ) * sizeof(float);
        if (ws_size >= need) { chunk = cand[i]; break; }
    }

    if (chunk == 0) {
        float* hbuf0 = ws;
        float* cbuf  = hbuf0 + HSLOT;
        float* hbuf1 = cbuf + HSLOT;
        hipMemsetAsync(hbuf0, 0, 2 * HSLOT * sizeof(float), stream);
        float* hin = hbuf0; float* hout = hbuf1;
        for (int s = 0; s < T_SEQ; ++s) {
            lstm_step_fb<<<dim3(16, 8, 2), 256, 0, stream>>>(
                tokens, emb, W_f, U_f, b_f, W_b, U_b, b_b, hin, hout, cbuf, s);
            float* tmp = hin; hin = hout; hout = tmp;
        }
        dense_softmax_v14<<<dim3(BATCH), 64, 0, stream>>>(hin, W_d, b_d, out);
        return;
    }

    float*    xw   = ws;                                    // [2][chunk][128][1024]
    float*    hA   = xw + (size_t)2 * chunk * BATCH * G4;
    float*    hB   = hA + HSLOT;
    float*    cbuf = hB + HSLOT;
    unsigned* bar  = (unsigned*)(cbuf + HSLOT);

    // zero h0, c0, barrier state (hB harmless, contiguous) every call
    hipMemsetAsync(hA, 0, (3 * HSLOT + BARSZ) * sizeof(float), stream);

    for (int c0 = 0; c0 < T_SEQ; c0 += chunk) {
        xw_gemm_v14<<<dim3(chunk * BATCH / 32, 8, 2), 256, 0, stream>>>(
            tokens, emb, W_f, b_f, W_b, b_b, xw, c0, chunk);
        lstm_scan_v14<<<dim3(16, 16, 2), 256, 0, stream>>>(
            xw, U_f, U_b, hA, hB, cbuf, bar, chunk);
        // chunk is even -> final h of this chunk ends in hA
    }
    dense_softmax_v14<<<dim3(BATCH), 64, 0, stream>>>(hA, W_d, b_d, out);
}

// Round 15
// 6119.145 us; speedup vs baseline: 3.4340x; 3.4340x over previous
//
#include <hip/hip_runtime.h>
#include <hip/hip_fp16.h>
#include <math.h>

#define T_SEQ  512
#define BATCH  128
#define HID    256
#define NCLS   20
#define G4     1024   // 4*HID

typedef _Float16 v2h __attribute__((ext_vector_type(2)));

__device__ __forceinline__ float fdot2_acc(unsigned a, unsigned b, float acc) {
#if __has_builtin(__builtin_amdgcn_fdot2)
    return __builtin_amdgcn_fdot2(__builtin_bit_cast(v2h, a),
                                  __builtin_bit_cast(v2h, b), acc, false);
#else
    __half2 a2 = __builtin_bit_cast(__half2, a);
    __half2 b2 = __builtin_bit_cast(__half2, b);
    acc = fmaf(__low2float(a2),  __low2float(b2),  acc);
    acc = fmaf(__high2float(a2), __high2float(b2), acc);
    return acc;
#endif
}

// ---------------------------------------------------------------------------
// Pack U (f32 [256][1024]) -> f16x2 over k-pairs: u16[dir][kp][col].
// ---------------------------------------------------------------------------
__global__ __launch_bounds__(256) void pack_u16_v15(
    const float* __restrict__ U_f, const float* __restrict__ U_b,
    unsigned* __restrict__ u16out)
{
    int idx = blockIdx.x * 256 + threadIdx.x;    // 0 .. 2*128*1024-1
    int dir = idx >> 17;
    int rem = idx & 131071;
    int kp  = rem >> 10;
    int col = rem & 1023;
    const float* __restrict__ U = dir ? U_b : U_f;
    __half2 h = __floats2half2_rn(U[(size_t)(2 * kp) * G4 + col],
                                  U[(size_t)(2 * kp + 1) * G4 + col]);
    u16out[idx] = *(unsigned*)&h;
}

// ---------------------------------------------------------------------------
// Kernel A: batched input projection (v13, proven).
// ---------------------------------------------------------------------------
__global__ __launch_bounds__(256) void xw_gemm_v15(
    const int*   __restrict__ tokens,
    const float* __restrict__ emb_table,
    const float* __restrict__ W_f, const float* __restrict__ b_f,
    const float* __restrict__ W_b, const float* __restrict__ b_b,
    float* __restrict__ xw, int chunk0, int chunk_len)
{
    const int dir = blockIdx.z;
    const float* __restrict__ W    = dir ? W_b : W_f;
    const float* __restrict__ bias = dir ? b_b : b_f;
    const int mtile = blockIdx.x;
    const int ntile = blockIdx.y;
    const int tid = threadIdx.x;

    __shared__ float At[256][32];
    __shared__ float Bs[32][128];
    __shared__ int   tok[32];

    if (tid < 32) {
        int m = mtile * 32 + tid;
        int s_local = m >> 7;
        int b = m & 127;
        int tt = chunk0 + s_local;
        if (dir) tt = T_SEQ - 1 - tt;
        int token = tokens[b * T_SEQ + tt];
        tok[tid] = token < 0 ? 0 : (token > 49999 ? 49999 : token);
    }
    __syncthreads();

    {
        int r = tid >> 3, c8 = tid & 7;
        const float4* src = (const float4*)(emb_table + (size_t)tok[r] * 256);
        #pragma unroll
        for (int i = 0; i < 8; ++i) {
            int c4 = c8 + i * 8;
            float4 v = src[c4];
            int k0 = c4 * 4;
            At[k0 + 0][r] = v.x; At[k0 + 1][r] = v.y;
            At[k0 + 2][r] = v.z; At[k0 + 3][r] = v.w;
        }
    }

    const int r0 = (tid >> 6) * 8;
    const int col0 = tid & 63;
    float acc0[8], acc1[8];
    {
        float bv0 = bias[ntile * 128 + col0];
        float bv1 = bias[ntile * 128 + col0 + 64];
        #pragma unroll
        for (int i = 0; i < 8; ++i) { acc0[i] = bv0; acc1[i] = bv1; }
    }

    for (int kc = 0; kc < 8; ++kc) {
        __syncthreads();
        #pragma unroll
        for (int i = 0; i < 4; ++i) {
            int idx = tid + i * 256;
            int row = idx >> 5, c4 = idx & 31;
            *(float4*)&Bs[row][c4 * 4] =
                *(const float4*)&W[(size_t)(kc * 32 + row) * G4 + ntile * 128 + c4 * 4];
        }
        __syncthreads();
        #pragma unroll 8
        for (int k = 0; k < 32; ++k) {
            float4 a0 = *(const float4*)&At[kc * 32 + k][r0];
            float4 a1 = *(const float4*)&At[kc * 32 + k][r0 + 4];
            float bb0 = Bs[k][col0];
            float bb1 = Bs[k][col0 + 64];
            acc0[0] = fmaf(a0.x, bb0, acc0[0]); acc1[0] = fmaf(a0.x, bb1, acc1[0]);
            acc0[1] = fmaf(a0.y, bb0, acc0[1]); acc1[1] = fmaf(a0.y, bb1, acc1[1]);
            acc0[2] = fmaf(a0.z, bb0, acc0[2]); acc1[2] = fmaf(a0.z, bb1, acc1[2]);
            acc0[3] = fmaf(a0.w, bb0, acc0[3]); acc1[3] = fmaf(a0.w, bb1, acc1[3]);
            acc0[4] = fmaf(a1.x, bb0, acc0[4]); acc1[4] = fmaf(a1.x, bb1, acc1[4]);
            acc0[5] = fmaf(a1.y, bb0, acc0[5]); acc1[5] = fmaf(a1.y, bb1, acc1[5]);
            acc0[6] = fmaf(a1.z, bb0, acc0[6]); acc1[6] = fmaf(a1.z, bb1, acc1[6]);
            acc0[7] = fmaf(a1.w, bb0, acc0[7]); acc1[7] = fmaf(a1.w, bb1, acc1[7]);
        }
    }

    #pragma unroll
    for (int i = 0; i < 8; ++i) {
        int m = mtile * 32 + r0 + i;
        int s_local = m >> 7, b = m & 127;
        size_t base = (((size_t)dir * chunk_len + s_local) * BATCH + b) * G4 + ntile * 128;
        xw[base + col0] = acc0[i];
        xw[base + col0 + 64] = acc1[i];
    }
}

// ---------------------------------------------------------------------------
// Kernel B: one LSTM step via f16x2 packed U + fdot2.
// grid (rt=16, ut=16, dir=2) = 512 blocks (2/CU), 256 threads.
// Block: 8 batch rows x 16 hidden units (64 gate-cols: g*256+ut*16+j).
// Thread (g,r,q): 2 cols c0=g*256+ut*16+q*2, c0+1. 128 kp-iters of
// {1 uint2 U load + 1 LDS h dword + 2 fdot2}.
// ---------------------------------------------------------------------------
__global__ __launch_bounds__(256) void lstm_step_v15(
    const float* __restrict__ xw_f, const float* __restrict__ xw_b, // [128][1024]
    const unsigned* __restrict__ u16,                               // [2][128][1024]
    const float* __restrict__ h_in, float* __restrict__ h_out,
    float* __restrict__ c_state)
{
    const int rt  = blockIdx.x;
    const int ut  = blockIdx.y;
    const int dir = blockIdx.z;
    const int tid = threadIdx.x;
    const float*    __restrict__ xw  = dir ? xw_b : xw_f;
    const unsigned* __restrict__ U16 = u16 + (size_t)dir * 131072;

    __shared__ unsigned hs16[8][130];   // h as f16x2 pairs over k
    __shared__ float    zs[4][8][16];

    // stage h -> f16x2 LDS
    for (int i = tid; i < 1024; i += 256) {
        int rr = i >> 7, kp = i & 127;
        float2 hv = *(const float2*)&h_in[((size_t)dir * BATCH + rt * 8 + rr) * HID + 2 * kp];
        __half2 hh = __floats2half2_rn(hv.x, hv.y);
        hs16[rr][kp] = *(unsigned*)&hh;
    }
    __syncthreads();

    const int g = tid >> 6, r = (tid >> 3) & 7, q = tid & 7;
    const int c0 = g * 256 + ut * 16 + q * 2;

    float2 xv = *(const float2*)&xw[(size_t)(rt * 8 + r) * G4 + c0];
    float acc0 = xv.x, acc1 = xv.y;
    const unsigned* __restrict__ Up = U16 + c0;

    #pragma unroll 16
    for (int kp = 0; kp < 128; ++kp) {
        unsigned hp = hs16[r][kp];
        uint2 uv = *(const uint2*)&Up[(size_t)kp * G4];
        acc0 = fdot2_acc(hp, uv.x, acc0);
        acc1 = fdot2_acc(hp, uv.y, acc1);
    }
    zs[g][r][q * 2]     = acc0;
    zs[g][r][q * 2 + 1] = acc1;
    __syncthreads();

    if (tid < 128) {
        const int r2 = tid >> 4, uu = tid & 15;
        float zi = zs[0][r2][uu];
        float zf = zs[1][r2][uu];
        float zg = zs[2][r2][uu];
        float zo = zs[3][r2][uu];
        float si = 1.0f / (1.0f + expf(-zi));
        float sf = 1.0f / (1.0f + expf(-zf));
        float tg = tanhf(zg);
        float so = 1.0f / (1.0f + expf(-zo));
        size_t idx = ((size_t)dir * BATCH + rt * 8 + r2) * HID + ut * 16 + uu;
        float cv = fmaf(sf, c_state[idx], si * tg);
        c_state[idx] = cv;
        h_out[idx] = so * tanhf(cv);
    }
}

// ---------------------------------------------------------------------------
// Fallback per-step kernel (v12 path) for tiny workspace.
// ---------------------------------------------------------------------------
__global__ __launch_bounds__(256) void lstm_step_fb(
    const int*   __restrict__ tokens,
    const float* __restrict__ emb_table,
    const float* __restrict__ W_f, const float* __restrict__ U_f, const float* __restrict__ b_f,
    const float* __restrict__ W_b, const float* __restrict__ U_b, const float* __restrict__ b_b,
    const float* __restrict__ h_in, float* __restrict__ h_out,
    float* __restrict__ c_state, int step)
{
    const int rt  = blockIdx.x;
    const int ut  = blockIdx.y;
    const int dir = blockIdx.z;
    const int tid = threadIdx.x;
    const float* __restrict__ W  = dir ? W_b : W_f;
    const float* __restrict__ U  = dir ? U_b : U_f;
    const float* __restrict__ bs = dir ? b_b : b_f;

    __shared__ int   tok[8];
    __shared__ float xs[8][260];
    __shared__ float hs[8][260];
    __shared__ float zsf[4][8][32];

    const int tt = dir ? (T_SEQ - 1 - step) : step;
    if (tid < 8) {
        int token = tokens[(rt * 8 + tid) * T_SEQ + tt];
        tok[tid] = (token < 0) ? 0 : (token > 49999 ? 49999 : token);
    }
    __syncthreads();
    for (int i = tid; i < 2048; i += 256) {
        int r = i >> 8, k = i & 255;
        xs[r][k] = emb_table[(size_t)tok[r] * 256 + k];
        hs[r][k] = h_in[((size_t)dir * BATCH + rt * 8 + r) * HID + k];
    }
    __syncthreads();

    const int g = tid >> 6, r = (tid >> 3) & 7, q = tid & 7;
    const int col = g * 256 + ut * 32 + q * 4;
    const float4* __restrict__ W4 = (const float4*)(W + col);
    const float4* __restrict__ U4 = (const float4*)(U + col);
    float4 acc = *(const float4*)(bs + col);
    #pragma unroll 4
    for (int k = 0; k < 256; ++k) {
        float xv = xs[r][k], hv = hs[r][k];
        float4 w = W4[(size_t)k * 256];
        float4 u = U4[(size_t)k * 256];
        acc.x = fmaf(xv, w.x, acc.x); acc.y = fmaf(xv, w.y, acc.y);
        acc.z = fmaf(xv, w.z, acc.z); acc.w = fmaf(xv, w.w, acc.w);
        acc.x = fmaf(hv, u.x, acc.x); acc.y = fmaf(hv, u.y, acc.y);
        acc.z = fmaf(hv, u.z, acc.z); acc.w = fmaf(hv, u.w, acc.w);
    }
    *(float4*)&zsf[g][r][q * 4] = acc;
    __syncthreads();
    {
        const int r2 = tid >> 5, j2 = tid & 31;
        float si = 1.0f / (1.0f + expf(-zsf[0][r2][j2]));
        float sf = 1.0f / (1.0f + expf(-zsf[1][r2][j2]));
        float tg = tanhf(zsf[2][r2][j2]);
        float so = 1.0f / (1.0f + expf(-zsf[3][r2][j2]));
        size_t idx = ((size_t)dir * BATCH + rt * 8 + r2) * HID + ut * 32 + j2;
        float cv = fmaf(sf, c_state[idx], si * tg);
        c_state[idx] = cv;
        h_out[idx] = so * tanhf(cv);
    }
}

// ---------------------------------------------------------------------------
// Dense + softmax (f32): one block per batch row.
// ---------------------------------------------------------------------------
__global__ __launch_bounds__(64) void dense_softmax_v15(
    const float* __restrict__ h_final,
    const float* __restrict__ W_d, const float* __restrict__ b_d,
    float* __restrict__ out)
{
    const int rrow = blockIdx.x;
    const int cth  = threadIdx.x;
    __shared__ float lg[NCLS];
    if (cth < NCLS) {
        const float* hf = h_final + (size_t)rrow * HID;
        const float* hb = h_final + ((size_t)BATCH + rrow) * HID;
        float s = b_d[cth];
        for (int k = 0; k < HID; ++k) s = fmaf(hf[k], W_d[k * NCLS + cth], s);
        for (int k = 0; k < HID; ++k) s = fmaf(hb[k], W_d[(HID + k) * NCLS + cth], s);
        lg[cth] = s;
    }
    __syncthreads();
    if (cth == 0) {
        float m = lg[0];
        for (int c = 1; c < NCLS; ++c) m = fmaxf(m, lg[c]);
        float e[NCLS]; float ssum = 0.0f;
        for (int c = 0; c < NCLS; ++c) { e[c] = expf(lg[c] - m); ssum += e[c]; }
        float inv = 1.0f / ssum;
        for (int c = 0; c < NCLS; ++c) out[rrow * NCLS + c] = e[c] * inv;
    }
}

extern "C" void kernel_launch(void* const* d_in, const int* in_sizes, int n_in,
                              void* d_out, int out_size, void* d_ws, size_t ws_size,
                              hipStream_t stream)
{
    const int*   tokens = (const int*)d_in[0];
    const float* emb    = (const float*)d_in[1];
    const float* W_f    = (const float*)d_in[2];
    const float* U_f    = (const float*)d_in[3];
    const float* b_f    = (const float*)d_in[4];
    const float* W_b    = (const float*)d_in[5];
    const float* U_b    = (const float*)d_in[6];
    const float* b_b    = (const float*)d_in[7];
    const float* W_d    = (const float*)d_in[8];
    const float* b_d    = (const float*)d_in[9];
    float* out = (float*)d_out;
    float* ws  = (float*)d_ws;

    const size_t HSLOT = (size_t)2 * BATCH * HID;        // 65536 floats
    const size_t U16SZ = (size_t)2 * 128 * G4;           // 262144 dwords
    int chunk = 0;
    const int cand[4] = {512, 128, 64, 16};
    for (int i = 0; i < 4; ++i) {
        size_t need = ((size_t)2 * cand[i] * BATCH * G4 + 3 * HSLOT + U16SZ) * sizeof(float);
        if (ws_size >= need) { chunk = cand[i]; break; }
    }

    if (chunk == 0) {
        float* hbuf0 = ws;
        float* cbuf  = hbuf0 + HSLOT;
        float* hbuf1 = cbuf + HSLOT;
        hipMemsetAsync(hbuf0, 0, 2 * HSLOT * sizeof(float), stream);
        float* hin = hbuf0; float* hout = hbuf1;
        for (int s = 0; s < T_SEQ; ++s) {
            lstm_step_fb<<<dim3(16, 8, 2), 256, 0, stream>>>(
                tokens, emb, W_f, U_f, b_f, W_b, U_b, b_b, hin, hout, cbuf, s);
            float* tmp = hin; hin = hout; hout = tmp;
        }
        dense_softmax_v15<<<dim3(BATCH), 64, 0, stream>>>(hin, W_d, b_d, out);
        return;
    }

    float*    xw   = ws;                                    // [2][chunk][128][1024]
    float*    hA   = xw + (size_t)2 * chunk * BATCH * G4;
    float*    hB   = hA + HSLOT;
    float*    cbuf = hB + HSLOT;
    unsigned* u16  = (unsigned*)(cbuf + HSLOT);

    hipMemsetAsync(hA, 0, 3 * HSLOT * sizeof(float), stream);   // h0 + c0 (+hB)

    pack_u16_v15<<<dim3(1024), 256, 0, stream>>>(U_f, U_b, u16);

    float* hin = hA; float* hout = hB;
    for (int c0 = 0; c0 < T_SEQ; c0 += chunk) {
        xw_gemm_v15<<<dim3(chunk * BATCH / 32, 8, 2), 256, 0, stream>>>(
            tokens, emb, W_f, b_f, W_b, b_b, xw, c0, chunk);
        for (int s = c0; s < c0 + chunk; ++s) {
            int sl = s - c0;
            const float* xwf = xw + (size_t)sl * BATCH * G4;
            const float* xwb = xw + ((size_t)chunk + sl) * BATCH * G4;
            lstm_step_v15<<<dim3(16, 16, 2), 256, 0, stream>>>(
                xwf, xwb, u16, hin, hout, cbuf);
            float* tmp = hin; hin = hout; hout = tmp;
        }
    }
    dense_softmax_v15<<<dim3(BATCH), 64, 0, stream>>>(hin, W_d, b_d, out);
}